// Round 10
// baseline (165.273 us; speedup 1.0000x reference)
//
#include <hip/hip_runtime.h>

#define B_ 32
#define T_ 64
#define I_ 256
#define H_ 512

static constexpr float ALPHA_F = 0.951229424500714f;   // exp(-1/20)
static constexpr float OMD_F   = 0.048770575499286f;   // 1 - decay
static constexpr float ETA_F   = 0.1f;
static constexpr float CSCALE  = 0.02f;                // 0.2 * ETA

// ---------------- fast tanh: exact at saturation, ~1e-6 rel elsewhere ----------------
__device__ __forceinline__ float tanh_fast(float x) {
  float xc = fminf(fmaxf(x, -15.f), 15.f);
  float e = __expf(2.f * xc);
  return (e - 1.f) * __builtin_amdgcn_rcpf(e + 1.f);
}

// ---------------- DPP full-wave (64-lane) sum; valid result in lane 63 ----------------
template <int CTRL>
__device__ __forceinline__ float dpp_add(float x) {
  int mv = __builtin_amdgcn_update_dpp(0, __float_as_int(x), CTRL, 0xF, 0xF, true);
  return x + __int_as_float(mv);
}
__device__ __forceinline__ float wave_sum_dpp(float x) {
  x = dpp_add<0x111>(x);  // row_shr:1
  x = dpp_add<0x112>(x);  // row_shr:2
  x = dpp_add<0x114>(x);  // row_shr:4
  x = dpp_add<0x118>(x);  // row_shr:8
  x = dpp_add<0x142>(x);  // row_bcast:15
  x = dpp_add<0x143>(x);  // row_bcast:31 -> lane63 = full 64-lane sum
  return x;
}

// ====== Kernel 1: projection GEMM + fused k-side scan epilogue ======
// m-tile == one batch (m = b*64 + t). k-half blocks (n0<512) scan their 64
// h-columns in-place (acc -> LDS -> 64-step recurrence) and write keys/ktg.
// v-half blocks write iv to ivbuf[b][t][hv].
__global__ __launch_bounds__(256) void proj_kscan(const float* __restrict__ x,
                                                  const float* __restrict__ W,
                                                  float* __restrict__ keys,
                                                  float* __restrict__ ktg,
                                                  float* __restrict__ ivbuf) {
  __shared__ float As[64][68];
  __shared__ float Bs[64][68];
  const int b  = blockIdx.x;
  const int n0 = blockIdx.y * 64;
  const int m0 = b * 64;
  const int tid = threadIdx.x;
  const int ty = tid >> 4, tx = tid & 15;
  float acc[4][4] = {};
  for (int k0 = 0; k0 < I_; k0 += 64) {
#pragma unroll
    for (int e = 0; e < 16; ++e) {
      int idx = tid + e * 256;
      int r = idx >> 6, c = idx & 63;
      As[r][c] = x[(size_t)(m0 + r) * I_ + k0 + c];
      Bs[r][c] = W[(size_t)(n0 + r) * I_ + k0 + c];
    }
    __syncthreads();
#pragma unroll 4
    for (int kq = 0; kq < 16; ++kq) {
      float4 a[4], bb[4];
#pragma unroll
      for (int i = 0; i < 4; ++i) a[i]  = *reinterpret_cast<const float4*>(&As[ty * 4 + i][kq * 4]);
#pragma unroll
      for (int j = 0; j < 4; ++j) bb[j] = *reinterpret_cast<const float4*>(&Bs[tx * 4 + j][kq * 4]);
#pragma unroll
      for (int i = 0; i < 4; ++i)
#pragma unroll
        for (int j = 0; j < 4; ++j)
          acc[i][j] += a[i].x * bb[j].x + a[i].y * bb[j].y
                     + a[i].z * bb[j].z + a[i].w * bb[j].w;
    }
    __syncthreads();
  }

  if (n0 < 512) {
    // stash acc -> As[t][hh] (t = ty*4+i, hh = tx*4+j)
#pragma unroll
    for (int i = 0; i < 4; ++i)
      *reinterpret_cast<float4*>(&As[ty * 4 + i][tx * 4]) =
          make_float4(acc[i][0], acc[i][1], acc[i][2], acc[i][3]);
    __syncthreads();
    if (tid < 64) {                       // wave 0: one h-column per lane
      float kv = 0.f, kt = 0.f;
      float* ko  = keys + (size_t)b * T_ * H_ + n0 + tid;
      float* kto = ktg  + (size_t)b * T_ * H_ + n0 + tid;
#pragma unroll 8
      for (int t = 0; t < T_; ++t) {
        kv = ALPHA_F * kv + As[t][tid];
        float k = tanh_fast(kv);
        kt = ALPHA_F * kt + OMD_F * k;
        ko[(size_t)t * H_]  = k;
        kto[(size_t)t * H_] = kt;
      }
    }
  } else {
    const int hv0 = n0 - 512;
#pragma unroll
    for (int i = 0; i < 4; ++i)
      *reinterpret_cast<float4*>(&ivbuf[((size_t)b * T_ + ty * 4 + i) * H_ + hv0 + tx * 4]) =
          make_float4(acc[i][0], acc[i][1], acc[i][2], acc[i][3]);
  }
}

// ====== Kernel 2: dots — C[b][t][s] = 0.02 * (k_t . kt_s) ======
__global__ __launch_bounds__(512) void dots_kernel(const float* __restrict__ keys,
                                                   const float* __restrict__ ktg,
                                                   float* __restrict__ C) {
  const int b = blockIdx.y;
  const int t = blockIdx.x * 8 + (threadIdx.x >> 6);
  const int lane = threadIdx.x & 63;
  const float* krow = keys + ((size_t)b * T_ + t) * H_ + 4 * lane;
  float4 k0 = *reinterpret_cast<const float4*>(krow);
  float4 k1 = *reinterpret_cast<const float4*>(krow + 256);
  const float* tb = ktg + (size_t)b * T_ * H_ + 4 * lane;
  float* Cb = C + ((size_t)b * T_ + t) * T_;
#pragma unroll 8
  for (int s = 0; s < T_; ++s) {
    const float* ar = tb + (size_t)s * H_;
    float4 a0 = *reinterpret_cast<const float4*>(ar);
    float4 a1 = *reinterpret_cast<const float4*>(ar + 256);
    float p = a0.x * k0.x + a0.y * k0.y + a0.z * k0.z + a0.w * k0.w
            + a1.x * k1.x + a1.y * k1.y + a1.z * k1.z + a1.w * k1.w;
    p = wave_sum_dpp(p);
    if (lane == 63) Cb[s] = CSCALE * p;
  }
}

// ====== Kernel 3: fused v-scan + mem GEMM, block = (b, i0) ======
// Wave 0 scans 64 h-columns (vqv in regs, C rows from global w/ ping-pong),
// writing vals + vt -> LDS. Then all 256 threads GEMM 64x512 (K=64) from LDS.
#define CASE4(Q) \
  case 4*Q+0: vqv[Q].x = vt; break; \
  case 4*Q+1: vqv[Q].y = vt; break; \
  case 4*Q+2: vqv[Q].z = vt; break; \
  case 4*Q+3: vqv[Q].w = vt; break;

#define VSTEP3(T_IDX, CUR, NXT)                                               \
  {                                                                           \
    const int tt = (T_IDX);                                                   \
    if (tt + 1 < T_) {                                                        \
      _Pragma("unroll")                                                       \
      for (int q = 0; q < 16; ++q)                                            \
        NXT[q] = reinterpret_cast<const float4*>(Cb + ((tt + 1) << 6))[q];    \
    }                                                                         \
    float p0 = 0.f, p1 = 0.f, p2 = 0.f, p3 = 0.f;                             \
    _Pragma("unroll")                                                         \
    for (int q = 0; q < 16; ++q) {                                            \
      p0 += CUR[q].x * vqv[q].x;                                              \
      p1 += CUR[q].y * vqv[q].y;                                              \
      p2 += CUR[q].z * vqv[q].z;                                              \
      p3 += CUR[q].w * vqv[q].w;                                              \
    }                                                                         \
    float ikv = (p0 + p1) + (p2 + p3);                                        \
    float ivc = iv0; iv0 = iv1;                                               \
    iv1 = (tt + 2 < T_) ? pv[(size_t)(tt + 2) * H_] : 0.f;                    \
    vv = ALPHA_F * vv + ivc + ikv;                                            \
    float v = tanh_fast(vv);                                                  \
    vt = ALPHA_F * vt + OMD_F * v;                                            \
    switch (tt) {                                                             \
      CASE4(0)  CASE4(1)  CASE4(2)  CASE4(3)                                  \
      CASE4(4)  CASE4(5)  CASE4(6)  CASE4(7)                                  \
      CASE4(8)  CASE4(9)  CASE4(10) CASE4(11)                                 \
      CASE4(12) CASE4(13) CASE4(14) CASE4(15)                                 \
    }                                                                         \
    vo[(size_t)tt * H_] = v;                                                  \
    Vt[(tt << 6) + tid] = vt;                                                 \
  }

__global__ __launch_bounds__(256, 1) void vscan_mem(const float* __restrict__ ivbuf,
                                                    const float* __restrict__ C,
                                                    const float* __restrict__ ktg,
                                                    float* __restrict__ vals,
                                                    float* __restrict__ mem) {
  extern __shared__ float smem[];
  float* ktL = smem;            // [64][512] fp32, 128 KB
  float* Vt  = smem + 32768;    // [64][64]  fp32, 16 KB
  const int i0  = blockIdx.x * 64;
  const int b   = blockIdx.y;
  const int tid = threadIdx.x;

  // stage kt history (8192 float4, coalesced)
  const float* ktb = ktg + (size_t)b * T_ * H_;
#pragma unroll
  for (int e = 0; e < 32; ++e)
    reinterpret_cast<float4*>(ktL)[tid + (e << 8)] =
        reinterpret_cast<const float4*>(ktb)[tid + (e << 8)];

  if (tid < 64) {
    const float* Cb = C + (size_t)b * T_ * T_;
    const float* pv = ivbuf + (size_t)b * T_ * H_ + i0 + tid;
    float* vo = vals + (size_t)b * T_ * H_ + i0 + tid;
    float vv = 0.f, vt = 0.f;
    float4 vqv[16];
#pragma unroll
    for (int q = 0; q < 16; ++q) vqv[q] = make_float4(0.f, 0.f, 0.f, 0.f);
    float iv0 = pv[0];
    float iv1 = pv[H_];
    float4 ca[16], cbuf[16];
#pragma unroll
    for (int q = 0; q < 16; ++q) ca[q] = reinterpret_cast<const float4*>(Cb)[q];
    for (int t2 = 0; t2 < T_; t2 += 2) {
      VSTEP3(t2,     ca,   cbuf)
      VSTEP3(t2 + 1, cbuf, ca)
    }
  }
  __syncthreads();   // ktL staged + Vt complete

  // mem GEMM: rows i0..i0+63, all 512 cols, K = 64
  const int ty = tid >> 4, tx = tid & 15;
  float* mb = mem + (size_t)b * H_ * H_ + (size_t)i0 * H_;
  for (int jp = 0; jp < 8; ++jp) {
    float acc[4][4] = {};
#pragma unroll 8
    for (int t = 0; t < 64; ++t) {
      float4 a  = *reinterpret_cast<const float4*>(&Vt[(t << 6) + ty * 4]);
      float4 bb = *reinterpret_cast<const float4*>(&ktL[(t << 9) + (jp << 6) + tx * 4]);
      float av[4] = {a.x, a.y, a.z, a.w};
      float bv[4] = {bb.x, bb.y, bb.z, bb.w};
#pragma unroll
      for (int i = 0; i < 4; ++i)
#pragma unroll
        for (int j = 0; j < 4; ++j) acc[i][j] += av[i] * bv[j];
    }
#pragma unroll
    for (int i = 0; i < 4; ++i)
      *reinterpret_cast<float4*>(&mb[(size_t)(ty * 4 + i) * H_ + (jp << 6) + tx * 4]) =
          make_float4(ETA_F * acc[i][0], ETA_F * acc[i][1],
                      ETA_F * acc[i][2], ETA_F * acc[i][3]);
  }
}

extern "C" void kernel_launch(void* const* d_in, const int* in_sizes, int n_in,
                              void* d_out, int out_size, void* d_ws, size_t ws_size,
                              hipStream_t stream) {
  const float* x = (const float*)d_in[0];   // (B,T,I)
  const float* W = (const float*)d_in[1];   // (2H,I)
  float* out = (float*)d_out;
  float* mem  = out;                             // B*H*H
  float* keys = out + (size_t)B_ * H_ * H_;      // B*T*H
  float* vals = keys + (size_t)B_ * T_ * H_;

  // all scratch in d_ws: ktg 4MB | ivbuf 4MB | C 0.5MB
  float* ktg   = (float*)d_ws;
  float* ivbuf = ktg + (size_t)B_ * T_ * H_;
  float* Cbuf  = ivbuf + (size_t)B_ * T_ * H_;

  (void)hipFuncSetAttribute((const void*)vscan_mem,
                            hipFuncAttributeMaxDynamicSharedMemorySize, 147456);

  proj_kscan<<<dim3(B_, 16), 256, 0, stream>>>(x, W, keys, ktg, ivbuf);
  dots_kernel<<<dim3(8, B_), 512, 0, stream>>>(keys, ktg, Cbuf);
  vscan_mem<<<dim3(8, B_), 256, 147456, stream>>>(ivbuf, Cbuf, ktg, vals, mem);
}

// Round 11
// 97.382 us; speedup vs baseline: 1.6972x; 1.6972x over previous
//
#include <hip/hip_runtime.h>

#define B_ 32
#define T_ 64
#define I_ 256
#define H_ 512

static constexpr float ALPHA_F = 0.951229424500714f;   // exp(-1/20)
static constexpr float OMD_F   = 0.048770575499286f;   // 1 - decay
static constexpr float ETA_F   = 0.1f;
static constexpr float CSCALE  = 0.02f;                // 0.2 * ETA

// ---------------- fast tanh: exact at saturation, ~1e-6 rel elsewhere ----------------
__device__ __forceinline__ float tanh_fast(float x) {
  float xc = fminf(fmaxf(x, -15.f), 15.f);
  float e = __expf(2.f * xc);
  return (e - 1.f) * __builtin_amdgcn_rcpf(e + 1.f);
}

// ---------------- DPP full-wave (64-lane) sum; valid result in lane 63 ----------------
template <int CTRL>
__device__ __forceinline__ float dpp_add(float x) {
  int mv = __builtin_amdgcn_update_dpp(0, __float_as_int(x), CTRL, 0xF, 0xF, true);
  return x + __int_as_float(mv);
}
__device__ __forceinline__ float wave_sum_dpp(float x) {
  x = dpp_add<0x111>(x);  // row_shr:1
  x = dpp_add<0x112>(x);  // row_shr:2
  x = dpp_add<0x114>(x);  // row_shr:4
  x = dpp_add<0x118>(x);  // row_shr:8
  x = dpp_add<0x142>(x);  // row_bcast:15
  x = dpp_add<0x143>(x);  // row_bcast:31 -> lane63 = full 64-lane sum
  return x;
}

// ====== Kernel 1: projection GEMM (R2 scalar-[65] core) + fused k-scan epilogue ======
// m-tile == one batch (m = b*64 + t). k-half blocks (n0<512) run the 64-step
// k-recurrence on their 64 h-columns and write keys/ktg. v-half writes ivbuf.
__global__ __launch_bounds__(256) void proj_kscan(const float* __restrict__ x,
                                                  const float* __restrict__ W,
                                                  float* __restrict__ keys,
                                                  float* __restrict__ ktg,
                                                  float* __restrict__ ivbuf) {
  __shared__ float As[64][65];
  __shared__ float Bs[64][65];
  const int b  = blockIdx.x;
  const int n0 = blockIdx.y * 64;
  const int m0 = b * 64;
  const int tid = threadIdx.x;
  const int ty = tid >> 4, tx = tid & 15;
  float acc[4][4] = {};
  for (int k0 = 0; k0 < I_; k0 += 64) {
#pragma unroll
    for (int e = 0; e < 16; ++e) {
      int idx = tid + e * 256;
      int r = idx >> 6, c = idx & 63;
      As[r][c] = x[(size_t)(m0 + r) * I_ + k0 + c];
      Bs[r][c] = W[(size_t)(n0 + r) * I_ + k0 + c];
    }
    __syncthreads();
#pragma unroll 8
    for (int kk = 0; kk < 64; ++kk) {
      float a[4], bb[4];
#pragma unroll
      for (int i = 0; i < 4; ++i) a[i] = As[ty * 4 + i][kk];
#pragma unroll
      for (int j = 0; j < 4; ++j) bb[j] = Bs[tx * 4 + j][kk];
#pragma unroll
      for (int i = 0; i < 4; ++i)
#pragma unroll
        for (int j = 0; j < 4; ++j) acc[i][j] += a[i] * bb[j];
    }
    __syncthreads();
  }

  if (n0 < 512) {
    // stash acc -> As[t][hh]  (t = ty*4+i, hh = tx*4+j)
#pragma unroll
    for (int i = 0; i < 4; ++i)
#pragma unroll
      for (int j = 0; j < 4; ++j) As[ty * 4 + i][tx * 4 + j] = acc[i][j];
    __syncthreads();
    if (tid < 64) {                       // wave 0: one h-column per lane
      float kv = 0.f, kt = 0.f;
      float* ko  = keys + (size_t)b * T_ * H_ + n0 + tid;
      float* kto = ktg  + (size_t)b * T_ * H_ + n0 + tid;
#pragma unroll 8
      for (int t = 0; t < T_; ++t) {
        kv = ALPHA_F * kv + As[t][tid];
        float k = tanh_fast(kv);
        kt = ALPHA_F * kt + OMD_F * k;
        ko[(size_t)t * H_]  = k;
        kto[(size_t)t * H_] = kt;
      }
    }
  } else {
    const int hv0 = n0 - 512;
#pragma unroll
    for (int i = 0; i < 4; ++i)
      *reinterpret_cast<float4*>(&ivbuf[((size_t)b * T_ + ty * 4 + i) * H_ + hv0 + tx * 4]) =
          make_float4(acc[i][0], acc[i][1], acc[i][2], acc[i][3]);
  }
}

// ====== Kernel 2: dots — C[b][t][s] = 0.02 * (k_t . kt_s) ======
__global__ __launch_bounds__(512) void dots_kernel(const float* __restrict__ keys,
                                                   const float* __restrict__ ktg,
                                                   float* __restrict__ C) {
  const int b = blockIdx.y;
  const int t = blockIdx.x * 8 + (threadIdx.x >> 6);
  const int lane = threadIdx.x & 63;
  const float* krow = keys + ((size_t)b * T_ + t) * H_ + 4 * lane;
  float4 k0 = *reinterpret_cast<const float4*>(krow);
  float4 k1 = *reinterpret_cast<const float4*>(krow + 256);
  const float* tb = ktg + (size_t)b * T_ * H_ + 4 * lane;
  float* Cb = C + ((size_t)b * T_ + t) * T_;
#pragma unroll 8
  for (int s = 0; s < T_; ++s) {
    const float* ar = tb + (size_t)s * H_;
    float4 a0 = *reinterpret_cast<const float4*>(ar);
    float4 a1 = *reinterpret_cast<const float4*>(ar + 256);
    float p = a0.x * k0.x + a0.y * k0.y + a0.z * k0.z + a0.w * k0.w
            + a1.x * k1.x + a1.y * k1.y + a1.z * k1.z + a1.w * k1.w;
    p = wave_sum_dpp(p);
    if (lane == 63) Cb[s] = CSCALE * p;
  }
}

// ====== Kernel 3: v-side scan — 1 wave/block, FULLY UNROLLED, all state in regs ======
// vv_t = a*vv + iv_t + sum_s C[t][s]*vt_s[h]; v=tanh(vv); vt_t = a*vt + (1-a)*v.
// iv: preloaded ivq[16] (64 loads in flight up-front). vt hist: vqv[16].
// C rows: LDS -> register ping-pong (ca/cbuf), one row ahead.
#define IVG(T) (((T) & 3) == 0 ? ivq[(T) >> 2].x : ((T) & 3) == 1 ? ivq[(T) >> 2].y \
              : ((T) & 3) == 2 ? ivq[(T) >> 2].z : ivq[(T) >> 2].w)
#define VQSET(T, val) do { \
    if (((T) & 3) == 0)      vqv[(T) >> 2].x = (val); \
    else if (((T) & 3) == 1) vqv[(T) >> 2].y = (val); \
    else if (((T) & 3) == 2) vqv[(T) >> 2].z = (val); \
    else                     vqv[(T) >> 2].w = (val); } while (0)

#define VSTEP(TT, CUR, NXT)                                                   \
  {                                                                           \
    if ((TT) + 1 < T_) {                                                      \
      _Pragma("unroll")                                                       \
      for (int q = 0; q < 16; ++q)                                            \
        NXT[q] = *reinterpret_cast<const float4*>(&Cs[(TT) + 1][4 * q]);      \
    }                                                                         \
    float p0 = 0.f, p1 = 0.f, p2 = 0.f, p3 = 0.f;                             \
    _Pragma("unroll")                                                         \
    for (int q = 0; q < 16; ++q) {                                            \
      p0 += CUR[q].x * vqv[q].x;                                              \
      p1 += CUR[q].y * vqv[q].y;                                              \
      p2 += CUR[q].z * vqv[q].z;                                              \
      p3 += CUR[q].w * vqv[q].w;                                              \
    }                                                                         \
    float ikv = (p0 + p1) + (p2 + p3);                                        \
    vv = ALPHA_F * vv + IVG(TT) + ikv;                                        \
    float v = tanh_fast(vv);                                                  \
    vt = ALPHA_F * vt + OMD_F * v;                                            \
    VQSET(TT, vt);                                                            \
    vo[(size_t)(TT) * H_]  = v;                                               \
    vto[(size_t)(TT) * H_] = vt;                                              \
  }

#define VP2(T2) VSTEP(T2, ca, cbuf) VSTEP((T2) + 1, cbuf, ca)
#define VP8(T8) VP2(T8) VP2((T8) + 2) VP2((T8) + 4) VP2((T8) + 6)
#define IVLD(Q) { ivq[Q].x = pv[(size_t)(4 * (Q) + 0) * H_]; \
                  ivq[Q].y = pv[(size_t)(4 * (Q) + 1) * H_]; \
                  ivq[Q].z = pv[(size_t)(4 * (Q) + 2) * H_]; \
                  ivq[Q].w = pv[(size_t)(4 * (Q) + 3) * H_]; }

__global__ __launch_bounds__(64, 1) void vscan_kernel(const float* __restrict__ ivbuf,
                                                      const float* __restrict__ C,
                                                      float* __restrict__ vals,
                                                      float* __restrict__ vtg) {
  __shared__ float Cs[T_][T_];   // 16 KB
  const int b    = blockIdx.x >> 3;
  const int lane = threadIdx.x;                 // 0..63
  const int h    = ((blockIdx.x & 7) << 6) + lane;

  const float* Cb = C + (size_t)b * T_ * T_;
#pragma unroll
  for (int e = 0; e < 16; ++e)
    reinterpret_cast<float4*>(&Cs[0][0])[lane + (e << 6)] =
        reinterpret_cast<const float4*>(Cb)[lane + (e << 6)];

  const float* pv = ivbuf + (size_t)b * T_ * H_ + h;
  float* vo  = vals + ((size_t)b * T_) * H_ + h;
  float* vto = vtg  + ((size_t)b * T_) * H_ + h;

  // preload all 64 iv values (independent loads, deep MLP)
  float4 ivq[16];
  IVLD(0)  IVLD(1)  IVLD(2)  IVLD(3)  IVLD(4)  IVLD(5)  IVLD(6)  IVLD(7)
  IVLD(8)  IVLD(9)  IVLD(10) IVLD(11) IVLD(12) IVLD(13) IVLD(14) IVLD(15)

  float vv = 0.f, vt = 0.f;
  float4 vqv[16];
#pragma unroll
  for (int q = 0; q < 16; ++q) vqv[q] = make_float4(0.f, 0.f, 0.f, 0.f);

  __syncthreads();   // Cs ready

  float4 ca[16], cbuf[16];
#pragma unroll
  for (int q = 0; q < 16; ++q)
    ca[q] = *reinterpret_cast<const float4*>(&Cs[0][4 * q]);

  VP8(0) VP8(8) VP8(16) VP8(24) VP8(32) VP8(40) VP8(48) VP8(56)
}

// ====== Kernel 4: mem = ETA * vt^T @ kt (per batch, K=T=64; R2 scalar-[65] core) ======
__global__ __launch_bounds__(256) void mem_gemm(const float* __restrict__ vtg,
                                                const float* __restrict__ ktg,
                                                float* __restrict__ mem) {
  const int b = blockIdx.z;
  const int i0 = blockIdx.y * 64;
  const int j0 = blockIdx.x * 64;
  __shared__ float Vs[64][65];
  __shared__ float Ks[64][65];
  const int tid = threadIdx.x;
  const int ty = tid >> 4, tx = tid & 15;
  const float* vb = vtg + (size_t)b * T_ * H_;
  const float* kb = ktg + (size_t)b * T_ * H_;
#pragma unroll
  for (int e = 0; e < 16; ++e) {
    int idx = tid + e * 256;
    int t = idx >> 6, c = idx & 63;
    Vs[t][c] = vb[(size_t)t * H_ + i0 + c];
    Ks[t][c] = kb[(size_t)t * H_ + j0 + c];
  }
  __syncthreads();
  float acc[4][4] = {};
#pragma unroll 8
  for (int t = 0; t < 64; ++t) {
    float a[4], bb[4];
#pragma unroll
    for (int i = 0; i < 4; ++i) a[i] = Vs[t][ty * 4 + i];
#pragma unroll
    for (int j = 0; j < 4; ++j) bb[j] = Ks[t][tx * 4 + j];
#pragma unroll
    for (int i = 0; i < 4; ++i)
#pragma unroll
      for (int j = 0; j < 4; ++j) acc[i][j] += a[i] * bb[j];
  }
  float* mb = mem + (size_t)b * H_ * H_;
#pragma unroll
  for (int i = 0; i < 4; ++i) {
    float4 o = make_float4(ETA_F * acc[i][0], ETA_F * acc[i][1],
                           ETA_F * acc[i][2], ETA_F * acc[i][3]);
    *reinterpret_cast<float4*>(&mb[(size_t)(i0 + ty * 4 + i) * H_ + j0 + tx * 4]) = o;
  }
}

extern "C" void kernel_launch(void* const* d_in, const int* in_sizes, int n_in,
                              void* d_out, int out_size, void* d_ws, size_t ws_size,
                              hipStream_t stream) {
  const float* x = (const float*)d_in[0];   // (B,T,I)
  const float* W = (const float*)d_in[1];   // (2H,I)
  float* out = (float*)d_out;
  float* mem  = out;                             // B*H*H
  float* keys = out + (size_t)B_ * H_ * H_;      // B*T*H
  float* vals = keys + (size_t)B_ * T_ * H_;

  // scratch in d_ws: ktg 4MB | ivbuf 4MB | vtg 4MB | C 0.5MB
  float* ktg   = (float*)d_ws;
  float* ivbuf = ktg + (size_t)B_ * T_ * H_;
  float* vtg   = ivbuf + (size_t)B_ * T_ * H_;
  float* Cbuf  = vtg + (size_t)B_ * T_ * H_;

  proj_kscan<<<dim3(B_, 16), 256, 0, stream>>>(x, W, keys, ktg, ivbuf);
  dots_kernel<<<dim3(8, B_), 512, 0, stream>>>(keys, ktg, Cbuf);
  vscan_kernel<<<dim3(8 * B_), 64, 0, stream>>>(ivbuf, Cbuf, vals, vtg);
  mem_gemm<<<dim3(8, 8, B_), 256, 0, stream>>>(vtg, ktg, mem);
}

// Round 12
// 85.754 us; speedup vs baseline: 1.9273x; 1.1356x over previous
//
#include <hip/hip_runtime.h>

#define B_ 32
#define T_ 64
#define I_ 256
#define H_ 512

static constexpr float ALPHA_F = 0.951229424500714f;   // exp(-1/20)
static constexpr float OMD_F   = 0.048770575499286f;   // 1 - decay
static constexpr float ETA_F   = 0.1f;
static constexpr float CSCALE  = 0.02f;                // 0.2 * ETA

// ---------------- fast tanh ----------------
__device__ __forceinline__ float tanh_fast(float x) {
  float xc = fminf(fmaxf(x, -15.f), 15.f);
  float e = __expf(2.f * xc);
  return (e - 1.f) * __builtin_amdgcn_rcpf(e + 1.f);
}

// ---------------- DPP full-wave sum; result in lane 63 ----------------
template <int CTRL>
__device__ __forceinline__ float dpp_add(float x) {
  int mv = __builtin_amdgcn_update_dpp(0, __float_as_int(x), CTRL, 0xF, 0xF, true);
  return x + __int_as_float(mv);
}
__device__ __forceinline__ float wave_sum_dpp(float x) {
  x = dpp_add<0x111>(x);
  x = dpp_add<0x112>(x);
  x = dpp_add<0x114>(x);
  x = dpp_add<0x118>(x);
  x = dpp_add<0x142>(x);
  x = dpp_add<0x143>(x);
  return x;
}

// ====== Kernel 1: projection GEMM (k-major LDS, b128 frags) + fused k-scan ======
// m-tile == one batch (m = b*64 + t). k-half blocks (n0<512) run the k-recurrence
// on their 64 h-columns, writing keys/ktg. v-half writes ivbuf.
__global__ __launch_bounds__(256) void proj_kscan(const float* __restrict__ x,
                                                  const float* __restrict__ W,
                                                  float* __restrict__ keys,
                                                  float* __restrict__ ktg,
                                                  float* __restrict__ ivbuf) {
  __shared__ float Ak[64][68];   // [kk][m], 272B rows (16B-aligned)
  __shared__ float Bk[64][68];   // [kk][n]
  const int b  = blockIdx.x;
  const int n0 = blockIdx.y * 64;
  const int m0 = b * 64;
  const int tid = threadIdx.x;
  const int ty = tid >> 4, tx = tid & 15;
  const int sr = tid >> 2;        // 0..63 (m or n index for staging)
  const int sc = tid & 3;         // base col-quad
  float acc[4][4] = {};

  for (int k0 = 0; k0 < I_; k0 += 64) {
    // stage transposed: float4 global load, 4 scalar LDS writes (2-way conflicts)
#pragma unroll
    for (int e = 0; e < 4; ++e) {
      const int cq = sc + 4 * e;  // 0..15 col-quad
      float4 xv = *reinterpret_cast<const float4*>(&x[(size_t)(m0 + sr) * I_ + k0 + cq * 4]);
      Ak[cq * 4 + 0][sr] = xv.x;
      Ak[cq * 4 + 1][sr] = xv.y;
      Ak[cq * 4 + 2][sr] = xv.z;
      Ak[cq * 4 + 3][sr] = xv.w;
      float4 wv = *reinterpret_cast<const float4*>(&W[(size_t)(n0 + sr) * I_ + k0 + cq * 4]);
      Bk[cq * 4 + 0][sr] = wv.x;
      Bk[cq * 4 + 1][sr] = wv.y;
      Bk[cq * 4 + 2][sr] = wv.z;
      Bk[cq * 4 + 3][sr] = wv.w;
    }
    __syncthreads();
#pragma unroll 8
    for (int kk = 0; kk < 64; ++kk) {
      float4 a4 = *reinterpret_cast<const float4*>(&Ak[kk][ty * 4]);
      float4 b4 = *reinterpret_cast<const float4*>(&Bk[kk][tx * 4]);
      float av[4] = {a4.x, a4.y, a4.z, a4.w};
      float bv[4] = {b4.x, b4.y, b4.z, b4.w};
#pragma unroll
      for (int i = 0; i < 4; ++i)
#pragma unroll
        for (int j = 0; j < 4; ++j) acc[i][j] += av[i] * bv[j];
    }
    __syncthreads();
  }

  if (n0 < 512) {
    // stash acc -> scratch[t][hh] (reuse Ak region), then wave 0 scans columns
    float* scr = &Ak[0][0];
#pragma unroll
    for (int i = 0; i < 4; ++i)
#pragma unroll
      for (int j = 0; j < 4; ++j) scr[(ty * 4 + i) * 68 + tx * 4 + j] = acc[i][j];
    __syncthreads();
    if (tid < 64) {
      float kv = 0.f, kt = 0.f;
      float* ko  = keys + (size_t)b * T_ * H_ + n0 + tid;
      float* kto = ktg  + (size_t)b * T_ * H_ + n0 + tid;
#pragma unroll 8
      for (int t = 0; t < T_; ++t) {
        kv = ALPHA_F * kv + scr[t * 68 + tid];
        float k = tanh_fast(kv);
        kt = ALPHA_F * kt + OMD_F * k;
        ko[(size_t)t * H_]  = k;
        kto[(size_t)t * H_] = kt;
      }
    }
  } else {
    const int hv0 = n0 - 512;
#pragma unroll
    for (int i = 0; i < 4; ++i)
      *reinterpret_cast<float4*>(&ivbuf[((size_t)b * T_ + ty * 4 + i) * H_ + hv0 + tx * 4]) =
          make_float4(acc[i][0], acc[i][1], acc[i][2], acc[i][3]);
  }
}

// ====== Kernel 2: dots — C[b][t][s] = 0.02 * (k_t . kt_s) ======
__global__ __launch_bounds__(512) void dots_kernel(const float* __restrict__ keys,
                                                   const float* __restrict__ ktg,
                                                   float* __restrict__ C) {
  const int b = blockIdx.y;
  const int t = blockIdx.x * 8 + (threadIdx.x >> 6);
  const int lane = threadIdx.x & 63;
  const float* krow = keys + ((size_t)b * T_ + t) * H_ + 4 * lane;
  float4 k0 = *reinterpret_cast<const float4*>(krow);
  float4 k1 = *reinterpret_cast<const float4*>(krow + 256);
  const float* tb = ktg + (size_t)b * T_ * H_ + 4 * lane;
  float* Cb = C + ((size_t)b * T_ + t) * T_;
#pragma unroll 8
  for (int s = 0; s < T_; ++s) {
    const float* ar = tb + (size_t)s * H_;
    float4 a0 = *reinterpret_cast<const float4*>(ar);
    float4 a1 = *reinterpret_cast<const float4*>(ar + 256);
    float p = a0.x * k0.x + a0.y * k0.y + a0.z * k0.z + a0.w * k0.w
            + a1.x * k1.x + a1.y * k1.y + a1.z * k1.z + a1.w * k1.w;
    p = wave_sum_dpp(p);
    if (lane == 63) Cb[s] = CSCALE * p;
  }
}

// ====== Kernel 3: v-side scan — 1 wave/block, fully unrolled, all state in regs ======
#define IVG(T) (((T) & 3) == 0 ? ivq[(T) >> 2].x : ((T) & 3) == 1 ? ivq[(T) >> 2].y \
              : ((T) & 3) == 2 ? ivq[(T) >> 2].z : ivq[(T) >> 2].w)
#define VQSET(T, val) do { \
    if (((T) & 3) == 0)      vqv[(T) >> 2].x = (val); \
    else if (((T) & 3) == 1) vqv[(T) >> 2].y = (val); \
    else if (((T) & 3) == 2) vqv[(T) >> 2].z = (val); \
    else                     vqv[(T) >> 2].w = (val); } while (0)

#define VSTEP(TT, CUR, NXT)                                                   \
  {                                                                           \
    if ((TT) + 1 < T_) {                                                      \
      _Pragma("unroll")                                                       \
      for (int q = 0; q < 16; ++q)                                            \
        NXT[q] = *reinterpret_cast<const float4*>(&Cs[(TT) + 1][4 * q]);      \
    }                                                                         \
    float p0 = 0.f, p1 = 0.f, p2 = 0.f, p3 = 0.f;                             \
    _Pragma("unroll")                                                         \
    for (int q = 0; q < 16; ++q) {                                            \
      p0 += CUR[q].x * vqv[q].x;                                              \
      p1 += CUR[q].y * vqv[q].y;                                              \
      p2 += CUR[q].z * vqv[q].z;                                              \
      p3 += CUR[q].w * vqv[q].w;                                              \
    }                                                                         \
    float ikv = (p0 + p1) + (p2 + p3);                                        \
    vv = ALPHA_F * vv + IVG(TT) + ikv;                                        \
    float v = tanh_fast(vv);                                                  \
    vt = ALPHA_F * vt + OMD_F * v;                                            \
    VQSET(TT, vt);                                                            \
    vo[(size_t)(TT) * H_]  = v;                                               \
    vto[(size_t)(TT) * H_] = vt;                                              \
  }

#define VP2(T2) VSTEP(T2, ca, cbuf) VSTEP((T2) + 1, cbuf, ca)
#define VP8(T8) VP2(T8) VP2((T8) + 2) VP2((T8) + 4) VP2((T8) + 6)
#define IVLD(Q) { ivq[Q].x = pv[(size_t)(4 * (Q) + 0) * H_]; \
                  ivq[Q].y = pv[(size_t)(4 * (Q) + 1) * H_]; \
                  ivq[Q].z = pv[(size_t)(4 * (Q) + 2) * H_]; \
                  ivq[Q].w = pv[(size_t)(4 * (Q) + 3) * H_]; }

__global__ __launch_bounds__(64, 1) void vscan_kernel(const float* __restrict__ ivbuf,
                                                      const float* __restrict__ C,
                                                      float* __restrict__ vals,
                                                      float* __restrict__ vtg) {
  __shared__ float Cs[T_][T_];   // 16 KB
  const int b    = blockIdx.x >> 3;
  const int lane = threadIdx.x;
  const int h    = ((blockIdx.x & 7) << 6) + lane;

  const float* Cb = C + (size_t)b * T_ * T_;
#pragma unroll
  for (int e = 0; e < 16; ++e)
    reinterpret_cast<float4*>(&Cs[0][0])[lane + (e << 6)] =
        reinterpret_cast<const float4*>(Cb)[lane + (e << 6)];

  const float* pv = ivbuf + (size_t)b * T_ * H_ + h;
  float* vo  = vals + ((size_t)b * T_) * H_ + h;
  float* vto = vtg  + ((size_t)b * T_) * H_ + h;

  float4 ivq[16];
  IVLD(0)  IVLD(1)  IVLD(2)  IVLD(3)  IVLD(4)  IVLD(5)  IVLD(6)  IVLD(7)
  IVLD(8)  IVLD(9)  IVLD(10) IVLD(11) IVLD(12) IVLD(13) IVLD(14) IVLD(15)

  float vv = 0.f, vt = 0.f;
  float4 vqv[16];
#pragma unroll
  for (int q = 0; q < 16; ++q) vqv[q] = make_float4(0.f, 0.f, 0.f, 0.f);

  __syncthreads();

  float4 ca[16], cbuf[16];
#pragma unroll
  for (int q = 0; q < 16; ++q)
    ca[q] = *reinterpret_cast<const float4*>(&Cs[0][4 * q]);

  VP8(0) VP8(8) VP8(16) VP8(24) VP8(32) VP8(40) VP8(48) VP8(56)
}

// ====== Kernel 4: mem = ETA * vt^T @ kt — k-major LDS (global already [t][h]), b128 frags ======
__global__ __launch_bounds__(256) void mem_gemm(const float* __restrict__ vtg,
                                                const float* __restrict__ ktg,
                                                float* __restrict__ mem) {
  const int b = blockIdx.z;
  const int i0 = blockIdx.y * 64;
  const int j0 = blockIdx.x * 64;
  __shared__ float Vs[64][68];   // [t][i], 272B rows
  __shared__ float Ks[64][68];   // [t][j]
  const int tid = threadIdx.x;
  const int ty = tid >> 4, tx = tid & 15;
  const float* vb = vtg + (size_t)b * T_ * H_;
  const float* kb = ktg + (size_t)b * T_ * H_;
#pragma unroll
  for (int e = 0; e < 16; ++e) {
    int idx = tid + e * 256;
    int t = idx >> 6, c = idx & 63;
    Vs[t][c] = vb[(size_t)t * H_ + i0 + c];
    Ks[t][c] = kb[(size_t)t * H_ + j0 + c];
  }
  __syncthreads();
  float acc[4][4] = {};
#pragma unroll 8
  for (int t = 0; t < 64; ++t) {
    float4 a4 = *reinterpret_cast<const float4*>(&Vs[t][ty * 4]);
    float4 b4 = *reinterpret_cast<const float4*>(&Ks[t][tx * 4]);
    float av[4] = {a4.x, a4.y, a4.z, a4.w};
    float bv[4] = {b4.x, b4.y, b4.z, b4.w};
#pragma unroll
    for (int i = 0; i < 4; ++i)
#pragma unroll
      for (int j = 0; j < 4; ++j) acc[i][j] += av[i] * bv[j];
  }
  float* mb = mem + (size_t)b * H_ * H_;
#pragma unroll
  for (int i = 0; i < 4; ++i) {
    float4 o = make_float4(ETA_F * acc[i][0], ETA_F * acc[i][1],
                           ETA_F * acc[i][2], ETA_F * acc[i][3]);
    *reinterpret_cast<float4*>(&mb[(size_t)(i0 + ty * 4 + i) * H_ + j0 + tx * 4]) = o;
  }
}

extern "C" void kernel_launch(void* const* d_in, const int* in_sizes, int n_in,
                              void* d_out, int out_size, void* d_ws, size_t ws_size,
                              hipStream_t stream) {
  const float* x = (const float*)d_in[0];   // (B,T,I)
  const float* W = (const float*)d_in[1];   // (2H,I)
  float* out = (float*)d_out;
  float* mem  = out;
  float* keys = out + (size_t)B_ * H_ * H_;
  float* vals = keys + (size_t)B_ * T_ * H_;

  // scratch in d_ws: ktg 4MB | ivbuf 4MB | vtg 4MB | C 0.5MB
  float* ktg   = (float*)d_ws;
  float* ivbuf = ktg + (size_t)B_ * T_ * H_;
  float* vtg   = ivbuf + (size_t)B_ * T_ * H_;
  float* Cbuf  = vtg + (size_t)B_ * T_ * H_;

  proj_kscan<<<dim3(B_, 16), 256, 0, stream>>>(x, W, keys, ktg, ivbuf);
  dots_kernel<<<dim3(8, B_), 512, 0, stream>>>(keys, ktg, Cbuf);
  vscan_kernel<<<dim3(8 * B_), 64, 0, stream>>>(ivbuf, Cbuf, vals, vtg);
  mem_gemm<<<dim3(8, 8, B_), 256, 0, stream>>>(vtg, ktg, mem);
}